// Round 3
// baseline (292.031 us; speedup 1.0000x reference)
//
#include <hip/hip_runtime.h>
#include <hip/hip_bf16.h>
#include <stdint.h>

constexpr int BB  = 64;    // batch
constexpr int SS  = 512;   // seq len
constexpr int HH  = 768;   // hidden
constexpr int NL  = 9;     // labels
constexpr int NROWS = BB * SS;          // 32768
constexpr int EMN   = SS * NL;          // 4608 emissions per batch
constexpr float L2E = 1.4426950408889634f;
constexpr float LN2 = 0.6931471805599453f;

__device__ __forceinline__ float readlane_f(float v, int lane) {
  union { float f; int i; } u;
  u.f = v;
  u.i = __builtin_amdgcn_readlane(u.i, lane);
  return u.f;
}

// ---------------------------------------------------------------------------
// Kernel 1: logits[b,s,l] = hidden[b,s,:] @ W[:,l] + bias[l]
// One wave per 4 rows, 2 rows in flight per iteration (butterfly latency
// overlaps across the two independent rows).
// ---------------------------------------------------------------------------
__global__ __launch_bounds__(256, 2) void logits_kernel(
    const float* __restrict__ hidden, const float* __restrict__ W,
    const float* __restrict__ bias, float* __restrict__ logits) {
  const int lane = threadIdx.x & 63;
  const int wid  = blockIdx.x * 4 + (threadIdx.x >> 6);   // 2048 blocks -> 8192 waves

  // Preload W fragments: element r = 4*lane + 256*j + k  (j=0..2, k=0..3)
  float w[3][4][NL];
#pragma unroll
  for (int j = 0; j < 3; ++j)
#pragma unroll
    for (int k = 0; k < 4; ++k) {
      const int r = lane * 4 + j * 256 + k;
#pragma unroll
      for (int l = 0; l < NL; ++l) w[j][k][l] = W[r * NL + l];
    }
  const float my_bias = (lane < NL) ? bias[lane] : 0.0f;

#pragma unroll
  for (int rep = 0; rep < 2; ++rep) {
    const int rA = wid + rep * 16384;
    const int rB = rA + 8192;
    const float4* hA = (const float4*)(hidden + (size_t)rA * HH);
    const float4* hB = (const float4*)(hidden + (size_t)rB * HH);
    float accA[NL], accB[NL];
#pragma unroll
    for (int l = 0; l < NL; ++l) { accA[l] = 0.0f; accB[l] = 0.0f; }
#pragma unroll
    for (int j = 0; j < 3; ++j) {
      const float4 a = hA[lane + j * 64];
      const float4 b = hB[lane + j * 64];
#pragma unroll
      for (int l = 0; l < NL; ++l) {
        accA[l] += a.x * w[j][0][l] + a.y * w[j][1][l] +
                   a.z * w[j][2][l] + a.w * w[j][3][l];
        accB[l] += b.x * w[j][0][l] + b.y * w[j][1][l] +
                   b.z * w[j][2][l] + b.w * w[j][3][l];
      }
    }
#pragma unroll
    for (int off = 32; off >= 1; off >>= 1)
#pragma unroll
      for (int l = 0; l < NL; ++l) {
        accA[l] += __shfl_xor(accA[l], off, 64);
        accB[l] += __shfl_xor(accB[l], off, 64);
      }
    if (lane < NL) {
      float vA = accA[0], vB = accB[0];
#pragma unroll
      for (int l = 1; l < NL; ++l)
        if (lane == l) { vA = accA[l]; vB = accB[l]; }
      logits[(size_t)rA * NL + lane] = vA + my_bias;
      logits[(size_t)rB * NL + lane] = vB + my_bias;
    }
  }
}

// ---------------------------------------------------------------------------
// Kernel 2: per-batch CRF. 192 blocks x 64 threads (1 wave).
//   role 0: log-normalizer (base-2 domain, readlane broadcast)
//   role 1: viterbi (exact ref arithmetic) + chunked-composition backtrace
//   role 2: numerator (gold-path score)
// ---------------------------------------------------------------------------
__global__ __launch_bounds__(64) void crf_kernel(
    const float* __restrict__ logits, const int* __restrict__ mask,
    const int* __restrict__ labels, const float* __restrict__ start_t,
    const float* __restrict__ end_t, const float* __restrict__ trans,
    float* __restrict__ out, float* __restrict__ num_den) {
  __shared__ __align__(16) float em_s[EMN + 16];   // padded for prefetch overrun
  __shared__ float tr_s[NL * NL];
  __shared__ int   lab[SS];
  __shared__ unsigned char bp_s[EMN + 80];         // padded for all-lane writes
  __shared__ unsigned char tags_s[SS];
  __shared__ int   len_s;

  const int role = blockIdx.x >> 6;
  const int b    = blockIdx.x & 63;
  const int tid  = threadIdx.x;
  const float esc = (role == 0) ? L2E : 1.0f;      // role 0 works in log2 domain

  // Stage emissions (float4, optionally scaled), transitions, length
  {
    const float4* src = (const float4*)(logits + (size_t)b * EMN);
    float4* dst = (float4*)em_s;
    for (int i = tid; i < EMN / 4; i += 64) {
      float4 v = src[i];
      v.x *= esc; v.y *= esc; v.z *= esc; v.w *= esc;
      dst[i] = v;
    }
  }
  for (int i = tid; i < NL * NL; i += 64) tr_s[i] = trans[i] * esc;
  int lsum = 0;
  for (int t = tid; t < SS; t += 64) lsum += mask[b * SS + t];
#pragma unroll
  for (int off = 32; off >= 1; off >>= 1) lsum += __shfl_xor(lsum, off, 64);
  if (tid == 0) len_s = lsum;
  if (role == 2) {
    for (int t = tid; t < SS; t += 64) {
      const int v = labels[b * SS + t];
      lab[t] = (v == -100) ? 0 : v;
    }
  }
  __syncthreads();
  const int len = len_s;   // in [256, 512]; mask[t] = (t < len)

  if (role == 0) {
    // ---- log-normalizer, base-2 domain ----
    const int j = (tid < NL) ? tid : 0;
    float tcol[NL];
#pragma unroll
    for (int i = 0; i < NL; ++i) tcol[i] = tr_s[i * NL + j];
    float s[NL];
#pragma unroll
    for (int i = 0; i < NL; ++i) s[i] = start_t[i] * L2E + em_s[i];
    float emj = em_s[NL + j];
    for (int t = 1; t < len; ++t) {
      const float emj_n = em_s[(t + 1) * NL + j];   // prefetch (padded)
      float c[NL];
#pragma unroll
      for (int i = 0; i < NL; ++i) c[i] = s[i] + tcol[i];
      const float m01 = fmaxf(c[0], c[1]), m23 = fmaxf(c[2], c[3]);
      const float m45 = fmaxf(c[4], c[5]), m67 = fmaxf(c[6], c[7]);
      const float m = fmaxf(fmaxf(fmaxf(m01, m23), fmaxf(m45, m67)), c[8]);
      float p[NL];
#pragma unroll
      for (int i = 0; i < NL; ++i) p[i] = exp2f(c[i] - m);
      const float s01 = p[0] + p[1], s23 = p[2] + p[3];
      const float s45 = p[4] + p[5], s67 = p[6] + p[7];
      const float sum = ((s01 + s23) + (s45 + s67)) + p[8];
      const float nxt = m + __log2f(sum) + emj;
#pragma unroll
      for (int i = 0; i < NL; ++i) s[i] = readlane_f(nxt, i);
      emj = emj_n;
    }
    float c[NL];
#pragma unroll
    for (int i = 0; i < NL; ++i) c[i] = s[i] + end_t[i] * L2E;
    const float m01 = fmaxf(c[0], c[1]), m23 = fmaxf(c[2], c[3]);
    const float m45 = fmaxf(c[4], c[5]), m67 = fmaxf(c[6], c[7]);
    const float m = fmaxf(fmaxf(fmaxf(m01, m23), fmaxf(m45, m67)), c[8]);
    float sum = 0.0f;
#pragma unroll
    for (int i = 0; i < NL; ++i) sum += exp2f(c[i] - m);
    if (tid == 0) num_den[64 + b] = (m + __log2f(sum)) * LN2;

  } else if (role == 1) {
    // ---- viterbi forward (exact reference arithmetic order) ----
    const int j = (tid < NL) ? tid : 0;
    float tcol[NL];
#pragma unroll
    for (int i = 0; i < NL; ++i) tcol[i] = tr_s[i * NL + j];
    float s[NL];
#pragma unroll
    for (int i = 0; i < NL; ++i) s[i] = start_t[i] + em_s[i];
    float emj = em_s[NL + j];
    for (int t = 1; t < len; ++t) {
      const float emj_n = em_s[(t + 1) * NL + j];
      float c[NL];
#pragma unroll
      for (int i = 0; i < NL; ++i) c[i] = s[i] + tcol[i];
      // first-max argmax tree (ties -> lowest index, == jnp.argmax)
      const bool b01 = c[0] >= c[1], b23 = c[2] >= c[3];
      const bool b45 = c[4] >= c[5], b67 = c[6] >= c[7];
      const float v01 = b01 ? c[0] : c[1]; const int i01 = b01 ? 0 : 1;
      const float v23 = b23 ? c[2] : c[3]; const int i23 = b23 ? 2 : 3;
      const float v45 = b45 ? c[4] : c[5]; const int i45 = b45 ? 4 : 5;
      const float v67 = b67 ? c[6] : c[7]; const int i67 = b67 ? 6 : 7;
      const bool bA = v01 >= v23, bB = v45 >= v67;
      const float vA = bA ? v01 : v23; const int iA = bA ? i01 : i23;
      const float vB = bB ? v45 : v67; const int iB = bB ? i45 : i67;
      const bool bC = vA >= vB;
      const float vC = bC ? vA : vB; const int iC = bC ? iA : iB;
      const bool bD = vC >= c[8];
      const float best = bD ? vC : c[8];
      const int   arg  = bD ? iC : 8;
      // all lanes write (lanes >=9 write garbage into later rows, which are
      // overwritten by their own step's lanes 0..8 before ever being read)
      bp_s[t * NL + tid] = (unsigned char)arg;
      const float nxt = best + emj;
#pragma unroll
      for (int i = 0; i < NL; ++i) s[i] = readlane_f(nxt, i);
      emj = emj_n;
    }
    // best last tag (uniform)
    float bv = s[0] + end_t[0];
    int   bl = 0;
#pragma unroll
    for (int i = 1; i < NL; ++i) {
      const float cc = s[i] + end_t[i];
      if (cc > bv) { bv = cc; bl = i; }
    }
    __syncthreads();   // bp_s visible / ordered

    // ---- backtrace via chunked map composition ----
    // Phase A: lane c composes steps t in [8c+1, 8c+8] into a 9-nibble map.
    uint64_t C = 0x876543210ULL;   // identity
#pragma unroll
    for (int k = 1; k <= 8; ++k) {
      const int t = 8 * tid + k;                  // t in [1, 512]
      uint64_t nc = 0;
#pragma unroll
      for (int x = 0; x < 9; ++x) {
        const int g = bp_s[t * NL + x] & 15;      // mask: garbage-safe shift
        nc |= ((C >> (4 * g)) & 15ULL) << (4 * x);
      }
      C = (t < len) ? nc : C;                     // t >= len: identity step
    }
    // Phase B: scalar chase over the 64 chunk maps (readlane chain).
    const uint32_t Clo = (uint32_t)C, Chi = (uint32_t)(C >> 32);
    uint32_t cur = (uint32_t)bl;                  // tag at position 512 (:= bl)
    int bnd = 0;                                  // lane c: tag at pos 8c+8
#pragma unroll
    for (int c = 63; c >= 0; --c) {
      bnd = (tid == c) ? (int)cur : bnd;          // capture boundary at lane c
      const uint32_t lo = (uint32_t)__builtin_amdgcn_readlane((int)Clo, c);
      const uint32_t hi = (uint32_t)__builtin_amdgcn_readlane((int)Chi, c);
      const uint64_t cc = ((uint64_t)hi << 32) | lo;
      cur = (uint32_t)((cc >> (4 * cur)) & 15u);
    }
    // Phase C: each lane re-walks its 8 steps emitting tags.
    int tag = bnd;
#pragma unroll
    for (int k = 8; k >= 1; --k) {
      const int t = 8 * tid + k;
      const int tt = (t < 512) ? t : 511;
      const int nt = bp_s[tt * NL + tag];
      tag = (t < len) ? nt : tag;
      tags_s[t - 1] = (unsigned char)tag;
    }
    __syncthreads();
    // one-hot * mask output (also writes the required zeros)
    for (int i = tid; i < EMN; i += 64) {
      const int t = i / NL;
      const int l = i - t * NL;
      out[1 + (size_t)b * EMN + i] =
          (t < len && l == (int)tags_s[t]) ? 1.0f : 0.0f;
    }

  } else {
    // ---- numerator (gold path score), parallel over t ----
    float contrib = 0.0f;
    for (int t = tid; t < SS; t += 64) {
      if (t >= 1 && t < len)
        contrib += em_s[t * NL + lab[t]] + tr_s[lab[t - 1] * NL + lab[t]];
    }
#pragma unroll
    for (int off = 32; off >= 1; off >>= 1)
      contrib += __shfl_xor(contrib, off, 64);
    if (tid == 0) {
      const int l0 = lab[0];
      num_den[b] = start_t[l0] + em_s[l0] + contrib + end_t[lab[len - 1]];
    }
  }
}

// ---------------------------------------------------------------------------
// Kernel 3: loss = -mean(num - den) = mean(den - num)
// ---------------------------------------------------------------------------
__global__ __launch_bounds__(64) void loss_kernel(
    const float* __restrict__ num_den, float* __restrict__ out) {
  const int tid = threadIdx.x;
  float v = num_den[64 + tid] - num_den[tid];
#pragma unroll
  for (int off = 32; off >= 1; off >>= 1) v += __shfl_xor(v, off, 64);
  if (tid == 0) out[0] = v * (1.0f / 64.0f);
}

extern "C" void kernel_launch(void* const* d_in, const int* in_sizes, int n_in,
                              void* d_out, int out_size, void* d_ws, size_t ws_size,
                              hipStream_t stream) {
  const float* hidden  = (const float*)d_in[0];
  const int*   mask    = (const int*)d_in[1];
  const int*   labels  = (const int*)d_in[2];
  const float* W       = (const float*)d_in[3];
  const float* bias    = (const float*)d_in[4];
  const float* start_t = (const float*)d_in[5];
  const float* end_t   = (const float*)d_in[6];
  const float* trans   = (const float*)d_in[7];
  float* out = (float*)d_out;

  float* logits  = (float*)d_ws;                 // 294912 floats
  float* num_den = logits + (size_t)NROWS * NL;  // 128 floats (num[64], den[64])

  logits_kernel<<<2048, 256, 0, stream>>>(hidden, W, bias, logits);
  crf_kernel<<<192, 64, 0, stream>>>(logits, mask, labels, start_t, end_t,
                                     trans, out, num_den);
  loss_kernel<<<1, 64, 0, stream>>>(num_den, out);
}

// Round 4
// 259.505 us; speedup vs baseline: 1.1253x; 1.1253x over previous
//
#include <hip/hip_runtime.h>
#include <hip/hip_bf16.h>
#include <stdint.h>

constexpr int BB  = 64;    // batch
constexpr int SS  = 512;   // seq len
constexpr int HH  = 768;   // hidden
constexpr int NL  = 9;     // labels
constexpr int NROWS = BB * SS;          // 32768
constexpr int EMN   = SS * NL;          // 4608 emissions per batch
constexpr int NSEG  = 8;                // time segments for parallel lognorm
constexpr float NEG  = -1e30f;

__device__ __forceinline__ float readlane_f(float v, int lane) {
  union { float f; int i; } u;
  u.f = v;
  u.i = __builtin_amdgcn_readlane(u.i, lane);
  return u.f;
}

// ---------------------------------------------------------------------------
// Kernel 1: logits[b,s,l] = hidden[b,s,:] @ W[:,l] + bias[l]
// One wave per 4 rows, 2 rows in flight. Blocks 0..63 additionally compute
// lens[b] = sum(mask[b]) so later kernels do a single scalar load.
// ---------------------------------------------------------------------------
__global__ __launch_bounds__(256, 2) void logits_kernel(
    const float* __restrict__ hidden, const float* __restrict__ W,
    const float* __restrict__ bias, const int* __restrict__ mask,
    float* __restrict__ logits, int* __restrict__ lens) {
  const int lane = threadIdx.x & 63;
  const int wid  = blockIdx.x * 4 + (threadIdx.x >> 6);   // 2048 blocks -> 8192 waves

  if (blockIdx.x < 64 && threadIdx.x < 64) {
    const int4* mp = (const int4*)(mask + blockIdx.x * SS);
    const int4 a = mp[threadIdx.x];
    const int4 c = mp[threadIdx.x + 64];
    int lsum = a.x + a.y + a.z + a.w + c.x + c.y + c.z + c.w;
#pragma unroll
    for (int off = 32; off >= 1; off >>= 1) lsum += __shfl_xor(lsum, off, 64);
    if (threadIdx.x == 0) lens[blockIdx.x] = lsum;
  }

  float w[3][4][NL];
#pragma unroll
  for (int j = 0; j < 3; ++j)
#pragma unroll
    for (int k = 0; k < 4; ++k) {
      const int r = lane * 4 + j * 256 + k;
#pragma unroll
      for (int l = 0; l < NL; ++l) w[j][k][l] = W[r * NL + l];
    }
  const float my_bias = (lane < NL) ? bias[lane] : 0.0f;

#pragma unroll
  for (int rep = 0; rep < 2; ++rep) {
    const int rA = wid + rep * 16384;
    const int rB = rA + 8192;
    const float4* hA = (const float4*)(hidden + (size_t)rA * HH);
    const float4* hB = (const float4*)(hidden + (size_t)rB * HH);
    float accA[NL], accB[NL];
#pragma unroll
    for (int l = 0; l < NL; ++l) { accA[l] = 0.0f; accB[l] = 0.0f; }
#pragma unroll
    for (int j = 0; j < 3; ++j) {
      const float4 a = hA[lane + j * 64];
      const float4 b = hB[lane + j * 64];
#pragma unroll
      for (int l = 0; l < NL; ++l) {
        accA[l] += a.x * w[j][0][l] + a.y * w[j][1][l] +
                   a.z * w[j][2][l] + a.w * w[j][3][l];
        accB[l] += b.x * w[j][0][l] + b.y * w[j][1][l] +
                   b.z * w[j][2][l] + b.w * w[j][3][l];
      }
    }
#pragma unroll
    for (int off = 32; off >= 1; off >>= 1)
#pragma unroll
      for (int l = 0; l < NL; ++l) {
        accA[l] += __shfl_xor(accA[l], off, 64);
        accB[l] += __shfl_xor(accB[l], off, 64);
      }
    if (lane < NL) {
      float vA = accA[0], vB = accB[0];
#pragma unroll
      for (int l = 1; l < NL; ++l)
        if (lane == l) { vA = accA[l]; vB = accB[l]; }
      logits[(size_t)rA * NL + lane] = vA + my_bias;
      logits[(size_t)rB * NL + lane] = vB + my_bias;
    }
  }
}

// ---------------------------------------------------------------------------
// Kernel 2: scan kernel, 4736 one-wave blocks.
//   blk   0..  63 : viterbi (sequential, bit-exact ref arithmetic) + backtrace
//   blk  64.. 127 : numerator (gold-path score), parallel over t
//   blk 128..4735 : lognorm segment scans: (b, seg, basis) -> one row of the
//                   segment's 9x9 semiring product matrix
// ---------------------------------------------------------------------------
__global__ __launch_bounds__(64) void scan_kernel(
    const float* __restrict__ logits, const int* __restrict__ labels,
    const float* __restrict__ start_t, const float* __restrict__ end_t,
    const float* __restrict__ trans, float* __restrict__ out,
    float* __restrict__ num_den, const int* __restrict__ lens,
    float* __restrict__ segmat) {
  __shared__ unsigned char bp_s[EMN + 80];
  __shared__ unsigned char tags_s[SS];
  __shared__ int lab[SS];

  const int blk = blockIdx.x;
  const int tid = threadIdx.x;
  const int j   = (tid < NL) ? tid : NL - 1;

  if (blk < 64) {
    // ================= viterbi =================
    const int b   = blk;
    const int len = lens[b];
    const float* emb = logits + (size_t)b * EMN;
    float tc[NL];
#pragma unroll
    for (int i = 0; i < NL; ++i) tc[i] = trans[i * NL + j];
    float s[NL];
#pragma unroll
    for (int i = 0; i < NL; ++i) s[i] = start_t[i] + emb[i];
    // 4-deep register prefetch of em[t][j]
    float eA = emb[1 * NL + j], eB = emb[2 * NL + j];
    float eC = emb[3 * NL + j], eD = emb[4 * NL + j];
    for (int t = 1; t < len; ++t) {
      float c[NL];
#pragma unroll
      for (int i = 0; i < NL; ++i) c[i] = s[i] + tc[i];
      // value path: pure max tree (exact, order-free) -> critical chain
      const float x01 = fmaxf(c[0], c[1]), x23 = fmaxf(c[2], c[3]);
      const float x45 = fmaxf(c[4], c[5]), x67 = fmaxf(c[6], c[7]);
      const float best = fmaxf(fmaxf(fmaxf(x01, x23), fmaxf(x45, x67)), c[8]);
      const float nxt = best + eA;
      // argmax path (first-max, == jnp.argmax), independent of value chain
      {
        const bool b01 = c[0] >= c[1], b23 = c[2] >= c[3];
        const bool b45 = c[4] >= c[5], b67 = c[6] >= c[7];
        const float v01 = b01 ? c[0] : c[1]; const int i01 = b01 ? 0 : 1;
        const float v23 = b23 ? c[2] : c[3]; const int i23 = b23 ? 2 : 3;
        const float v45 = b45 ? c[4] : c[5]; const int i45 = b45 ? 4 : 5;
        const float v67 = b67 ? c[6] : c[7]; const int i67 = b67 ? 6 : 7;
        const bool bA = v01 >= v23, bB = v45 >= v67;
        const float vA = bA ? v01 : v23; const int iA = bA ? i01 : i23;
        const float vB = bB ? v45 : v67; const int iB = bB ? i45 : i67;
        const bool bC = vA >= vB;
        const float vC = bC ? vA : vB; const int iC = bC ? iA : iB;
        const bool bD = vC >= c[8];
        const int arg = bD ? iC : 8;
        bp_s[t * NL + tid] = (unsigned char)arg;   // all lanes; pad-safe
      }
#pragma unroll
      for (int i = 0; i < NL; ++i) s[i] = readlane_f(nxt, i);
      eA = eB; eB = eC; eC = eD;
      eD = emb[(t + 4) * NL + j];   // overruns into segmat region at most: safe
    }
    float bv = s[0] + end_t[0];
    int   bl = 0;
#pragma unroll
    for (int i = 1; i < NL; ++i) {
      const float cc = s[i] + end_t[i];
      if (cc > bv) { bv = cc; bl = i; }
    }
    __syncthreads();

    // backtrace: chunked map composition (verified R3)
    uint64_t C = 0x876543210ULL;
#pragma unroll
    for (int k = 1; k <= 8; ++k) {
      const int t = 8 * tid + k;
      uint64_t nc = 0;
#pragma unroll
      for (int x = 0; x < 9; ++x) {
        const int g = bp_s[t * NL + x] & 15;
        nc |= ((C >> (4 * g)) & 15ULL) << (4 * x);
      }
      C = (t < len) ? nc : C;
    }
    const uint32_t Clo = (uint32_t)C, Chi = (uint32_t)(C >> 32);
    uint32_t cur = (uint32_t)bl;
    int bnd = 0;
#pragma unroll
    for (int c = 63; c >= 0; --c) {
      bnd = (tid == c) ? (int)cur : bnd;
      const uint32_t lo = (uint32_t)__builtin_amdgcn_readlane((int)Clo, c);
      const uint32_t hi = (uint32_t)__builtin_amdgcn_readlane((int)Chi, c);
      const uint64_t cc = ((uint64_t)hi << 32) | lo;
      cur = (uint32_t)((cc >> (4 * cur)) & 15u);
    }
    int tag = bnd;
#pragma unroll
    for (int k = 8; k >= 1; --k) {
      const int t = 8 * tid + k;
      const int tt = (t < 512) ? t : 511;
      const int nt = bp_s[tt * NL + tag];
      tag = (t < len) ? nt : tag;
      tags_s[t - 1] = (unsigned char)tag;
    }
    __syncthreads();
    for (int i = tid; i < EMN; i += 64) {
      const int t = i / NL;
      const int l = i - t * NL;
      out[1 + (size_t)b * EMN + i] =
          (t < len && l == (int)tags_s[t]) ? 1.0f : 0.0f;
    }

  } else if (blk < 128) {
    // ================= numerator =================
    const int b   = blk - 64;
    const int len = lens[b];
    const float* emb = logits + (size_t)b * EMN;
    for (int t = tid; t < SS; t += 64) {
      const int v = labels[b * SS + t];
      lab[t] = (v == -100) ? 0 : v;
    }
    __syncthreads();
    float contrib = 0.0f;
    for (int t = tid; t < SS; t += 64) {
      if (t >= 1 && t < len)
        contrib += emb[t * NL + lab[t]] + trans[lab[t - 1] * NL + lab[t]];
    }
#pragma unroll
    for (int off = 32; off >= 1; off >>= 1)
      contrib += __shfl_xor(contrib, off, 64);
    if (tid == 0) {
      const int l0 = lab[0];
      num_den[b] = start_t[l0] + emb[l0] + contrib + end_t[lab[len - 1]];
    }

  } else {
    // ================= lognorm segment scan =================
    const int id  = blk - 128;         // 0..4607
    const int b   = id / 72;
    const int rem = id - b * 72;
    const int sg  = rem / 9;
    const int e   = rem - sg * 9;      // basis state
    const int len = lens[b];
    const float* emb = logits + (size_t)b * EMN;
    float tc[NL];
#pragma unroll
    for (int i = 0; i < NL; ++i) tc[i] = trans[i * NL + j];
    float s[NL];
#pragma unroll
    for (int i = 0; i < NL; ++i) s[i] = (i == e) ? 0.0f : NEG;
    float my = (j == e) ? 0.0f : NEG;  // lane j's own current value
    const int tbeg = 64 * sg + 1;
    const int tlast = (64 * sg + 64 < 511) ? 64 * sg + 64 : 511;
    float eA = emb[tbeg * NL + j],       eB = emb[(tbeg + 1) * NL + j];
    float eC = emb[(tbeg + 2) * NL + j], eD = emb[(tbeg + 3) * NL + j];
    for (int t = tbeg; t <= tlast; ++t) {
      if (t >= len) break;             // mask is a prefix: remaining = identity
      float c[NL];
#pragma unroll
      for (int i = 0; i < NL; ++i) c[i] = s[i] + tc[i];
      const float x01 = fmaxf(c[0], c[1]), x23 = fmaxf(c[2], c[3]);
      const float x45 = fmaxf(c[4], c[5]), x67 = fmaxf(c[6], c[7]);
      const float m = fmaxf(fmaxf(fmaxf(x01, x23), fmaxf(x45, x67)), c[8]);
      float sum = 0.0f;
#pragma unroll
      for (int i = 0; i < NL; ++i) sum += __expf(c[i] - m);
      const float nxt = m + __logf(sum) + eA;
      my = nxt;
#pragma unroll
      for (int i = 0; i < NL; ++i) s[i] = readlane_f(nxt, i);
      eA = eB; eB = eC; eC = eD;
      eD = emb[(t + 4) * NL + j];
    }
    if (tid < NL)
      segmat[((size_t)(b * NSEG + sg) * NL + e) * NL + tid] = my;
  }
}

// ---------------------------------------------------------------------------
// Kernel 3: combine — per batch, chain the 8 segment matrices onto the
// initial vector, then den = logsumexp(v + end_t). One wave per batch.
// ---------------------------------------------------------------------------
__global__ __launch_bounds__(64) void combine_kernel(
    const float* __restrict__ logits, const float* __restrict__ segmat,
    const float* __restrict__ start_t, const float* __restrict__ end_t,
    float* __restrict__ num_den) {
  const int b   = blockIdx.x;
  const int tid = threadIdx.x;
  const int j   = (tid < NL) ? tid : NL - 1;
  float s[NL];
#pragma unroll
  for (int i = 0; i < NL; ++i) s[i] = start_t[i] + logits[(size_t)b * EMN + i];
  // double-buffered matrix column loads
  float mcur[NL], mnxt[NL];
  {
    const float* M = segmat + (size_t)(b * NSEG) * 81;
#pragma unroll
    for (int i = 0; i < NL; ++i) mcur[i] = M[i * NL + j];
  }
  for (int sg = 0; sg < NSEG; ++sg) {
    if (sg + 1 < NSEG) {
      const float* M = segmat + (size_t)(b * NSEG + sg + 1) * 81;
#pragma unroll
      for (int i = 0; i < NL; ++i) mnxt[i] = M[i * NL + j];
    }
    float c[NL];
#pragma unroll
    for (int i = 0; i < NL; ++i) c[i] = s[i] + mcur[i];
    const float x01 = fmaxf(c[0], c[1]), x23 = fmaxf(c[2], c[3]);
    const float x45 = fmaxf(c[4], c[5]), x67 = fmaxf(c[6], c[7]);
    const float m = fmaxf(fmaxf(fmaxf(x01, x23), fmaxf(x45, x67)), c[8]);
    float sum = 0.0f;
#pragma unroll
    for (int i = 0; i < NL; ++i) sum += __expf(c[i] - m);
    const float nxt = m + __logf(sum);
#pragma unroll
    for (int i = 0; i < NL; ++i) s[i] = readlane_f(nxt, i);
#pragma unroll
    for (int i = 0; i < NL; ++i) mcur[i] = mnxt[i];
  }
  float c[NL];
#pragma unroll
  for (int i = 0; i < NL; ++i) c[i] = s[i] + end_t[i];
  const float x01 = fmaxf(c[0], c[1]), x23 = fmaxf(c[2], c[3]);
  const float x45 = fmaxf(c[4], c[5]), x67 = fmaxf(c[6], c[7]);
  const float m = fmaxf(fmaxf(fmaxf(x01, x23), fmaxf(x45, x67)), c[8]);
  float sum = 0.0f;
#pragma unroll
  for (int i = 0; i < NL; ++i) sum += __expf(c[i] - m);
  if (tid == 0) num_den[64 + b] = m + __logf(sum);
}

// ---------------------------------------------------------------------------
// Kernel 4: loss = mean(den - num)
// ---------------------------------------------------------------------------
__global__ __launch_bounds__(64) void loss_kernel(
    const float* __restrict__ num_den, float* __restrict__ out) {
  const int tid = threadIdx.x;
  float v = num_den[64 + tid] - num_den[tid];
#pragma unroll
  for (int off = 32; off >= 1; off >>= 1) v += __shfl_xor(v, off, 64);
  if (tid == 0) out[0] = v * (1.0f / 64.0f);
}

extern "C" void kernel_launch(void* const* d_in, const int* in_sizes, int n_in,
                              void* d_out, int out_size, void* d_ws, size_t ws_size,
                              hipStream_t stream) {
  const float* hidden  = (const float*)d_in[0];
  const int*   mask    = (const int*)d_in[1];
  const int*   labels  = (const int*)d_in[2];
  const float* W       = (const float*)d_in[3];
  const float* bias    = (const float*)d_in[4];
  const float* start_t = (const float*)d_in[5];
  const float* end_t   = (const float*)d_in[6];
  const float* trans   = (const float*)d_in[7];
  float* out = (float*)d_out;

  float* logits  = (float*)d_ws;                      // 294912 floats
  float* segmat  = logits + (size_t)NROWS * NL;       // 64*8*81 = 41472 floats
  float* num_den = segmat + (size_t)BB * NSEG * 81;   // 128 floats
  int*   lens    = (int*)(num_den + 128);             // 64 ints

  logits_kernel<<<2048, 256, 0, stream>>>(hidden, W, bias, mask, logits, lens);
  scan_kernel<<<4736, 64, 0, stream>>>(logits, labels, start_t, end_t, trans,
                                       out, num_den, lens, segmat);
  combine_kernel<<<64, 64, 0, stream>>>(logits, segmat, start_t, end_t, num_den);
  loss_kernel<<<1, 64, 0, stream>>>(num_den, out);
}

// Round 5
// 258.545 us; speedup vs baseline: 1.1295x; 1.0037x over previous
//
#include <hip/hip_runtime.h>
#include <hip/hip_bf16.h>
#include <stdint.h>

constexpr int BB  = 64;    // batch
constexpr int SS  = 512;   // seq len
constexpr int HH  = 768;   // hidden
constexpr int NL  = 9;     // labels
constexpr int NROWS = BB * SS;          // 32768
constexpr int EMN   = SS * NL;          // 4608 emissions per batch
constexpr int NSEG  = 8;                // time segments for parallel lognorm
constexpr float NEG  = -1e30f;

__device__ __forceinline__ float readlane_f(float v, int lane) {
  union { float f; int i; } u;
  u.f = v;
  u.i = __builtin_amdgcn_readlane(u.i, lane);
  return u.f;
}

// ---------------------------------------------------------------------------
// Kernel 1: logits[b,s,l] = hidden[b,s,:] @ W[:,l] + bias[l]
// One wave per 4 rows, all 4 in flight (butterfly chains interleave).
// Blocks 0..63 additionally compute lens[b].
// ---------------------------------------------------------------------------
__global__ __launch_bounds__(256, 2) void logits_kernel(
    const float* __restrict__ hidden, const float* __restrict__ W,
    const float* __restrict__ bias, const int* __restrict__ mask,
    float* __restrict__ logits, int* __restrict__ lens) {
  const int lane = threadIdx.x & 63;
  const int wid  = blockIdx.x * 4 + (threadIdx.x >> 6);   // 8192 waves

  if (blockIdx.x < 64 && threadIdx.x < 64) {
    const int4* mp = (const int4*)(mask + blockIdx.x * SS);
    const int4 a = mp[threadIdx.x];
    const int4 c = mp[threadIdx.x + 64];
    int lsum = a.x + a.y + a.z + a.w + c.x + c.y + c.z + c.w;
#pragma unroll
    for (int off = 32; off >= 1; off >>= 1) lsum += __shfl_xor(lsum, off, 64);
    if (threadIdx.x == 0) lens[blockIdx.x] = lsum;
  }

  float w[3][4][NL];
#pragma unroll
  for (int j = 0; j < 3; ++j)
#pragma unroll
    for (int k = 0; k < 4; ++k) {
      const int r = lane * 4 + j * 256 + k;
#pragma unroll
      for (int l = 0; l < NL; ++l) w[j][k][l] = W[r * NL + l];
    }
  const float my_bias = (lane < NL) ? bias[lane] : 0.0f;

  // 4 rows in flight
  float4 h[4][3];
#pragma unroll
  for (int r = 0; r < 4; ++r) {
    const float4* hp = (const float4*)(hidden + (size_t)(wid + r * 8192) * HH);
#pragma unroll
    for (int j = 0; j < 3; ++j) h[r][j] = hp[lane + j * 64];
  }
  float acc[4][NL];
#pragma unroll
  for (int r = 0; r < 4; ++r)
#pragma unroll
    for (int l = 0; l < NL; ++l) acc[r][l] = 0.0f;
#pragma unroll
  for (int r = 0; r < 4; ++r)
#pragma unroll
    for (int j = 0; j < 3; ++j)
#pragma unroll
      for (int l = 0; l < NL; ++l)
        acc[r][l] += h[r][j].x * w[j][0][l] + h[r][j].y * w[j][1][l] +
                     h[r][j].z * w[j][2][l] + h[r][j].w * w[j][3][l];
#pragma unroll
  for (int off = 32; off >= 1; off >>= 1)
#pragma unroll
    for (int r = 0; r < 4; ++r)
#pragma unroll
      for (int l = 0; l < NL; ++l)
        acc[r][l] += __shfl_xor(acc[r][l], off, 64);
  if (lane < NL) {
#pragma unroll
    for (int r = 0; r < 4; ++r) {
      float v = acc[r][0];
#pragma unroll
      for (int l = 1; l < NL; ++l) if (lane == l) v = acc[r][l];
      logits[(size_t)(wid + r * 8192) * NL + lane] = v + my_bias;
    }
  }
}

// ---------------------------------------------------------------------------
// Kernel 2: scan kernel, 1664 one-wave blocks.
//   blk   0..  63 : viterbi (bit-exact ref arithmetic) + backtrace
//   blk  64.. 127 : numerator (gold-path score), parallel over t
//   blk 128..1663 : lognorm segment scans, 3 basis chains per wave (ILP-3)
// ---------------------------------------------------------------------------
__global__ __launch_bounds__(64) void scan_kernel(
    const float* __restrict__ logits, const int* __restrict__ labels,
    const float* __restrict__ start_t, const float* __restrict__ end_t,
    const float* __restrict__ trans, float* __restrict__ out,
    float* __restrict__ num_den, const int* __restrict__ lens,
    float* __restrict__ segmat) {
  __shared__ unsigned char bp_s[EMN + 80];
  __shared__ unsigned char tags_s[SS];
  __shared__ int lab[SS];

  const int blk = blockIdx.x;
  const int tid = threadIdx.x;
  const int j   = (tid < NL) ? tid : NL - 1;

  if (blk < 64) {
    // ================= viterbi =================
    const int b   = blk;
    const int len = lens[b];
    const float* emb = logits + (size_t)b * EMN;
    float tc[NL];
#pragma unroll
    for (int i = 0; i < NL; ++i) tc[i] = trans[i * NL + j];
    float s[NL];
#pragma unroll
    for (int i = 0; i < NL; ++i) s[i] = start_t[i] + emb[i];
    float eA = emb[1 * NL + j], eB = emb[2 * NL + j];
    float eC = emb[3 * NL + j], eD = emb[4 * NL + j];
    for (int t = 1; t < len; ++t) {
      float c[NL];
#pragma unroll
      for (int i = 0; i < NL; ++i) c[i] = s[i] + tc[i];
      const float x01 = fmaxf(c[0], c[1]), x23 = fmaxf(c[2], c[3]);
      const float x45 = fmaxf(c[4], c[5]), x67 = fmaxf(c[6], c[7]);
      const float best = fmaxf(fmaxf(fmaxf(x01, x23), fmaxf(x45, x67)), c[8]);
      const float nxt = best + eA;
      {
        const bool b01 = c[0] >= c[1], b23 = c[2] >= c[3];
        const bool b45 = c[4] >= c[5], b67 = c[6] >= c[7];
        const float v01 = b01 ? c[0] : c[1]; const int i01 = b01 ? 0 : 1;
        const float v23 = b23 ? c[2] : c[3]; const int i23 = b23 ? 2 : 3;
        const float v45 = b45 ? c[4] : c[5]; const int i45 = b45 ? 4 : 5;
        const float v67 = b67 ? c[6] : c[7]; const int i67 = b67 ? 6 : 7;
        const bool bA = v01 >= v23, bB = v45 >= v67;
        const float vA = bA ? v01 : v23; const int iA = bA ? i01 : i23;
        const float vB = bB ? v45 : v67; const int iB = bB ? i45 : i67;
        const bool bC = vA >= vB;
        const float vC = bC ? vA : vB; const int iC = bC ? iA : iB;
        const bool bD = vC >= c[8];
        const int arg = bD ? iC : 8;
        bp_s[t * NL + tid] = (unsigned char)arg;
      }
#pragma unroll
      for (int i = 0; i < NL; ++i) s[i] = readlane_f(nxt, i);
      eA = eB; eB = eC; eC = eD;
      eD = emb[(t + 4) * NL + j];
    }
    float bv = s[0] + end_t[0];
    int   bl = 0;
#pragma unroll
    for (int i = 1; i < NL; ++i) {
      const float cc = s[i] + end_t[i];
      if (cc > bv) { bv = cc; bl = i; }
    }
    __syncthreads();

    // backtrace: chunked map composition
    uint64_t C = 0x876543210ULL;
#pragma unroll
    for (int k = 1; k <= 8; ++k) {
      const int t = 8 * tid + k;
      uint64_t nc = 0;
#pragma unroll
      for (int x = 0; x < 9; ++x) {
        const int g = bp_s[t * NL + x] & 15;
        nc |= ((C >> (4 * g)) & 15ULL) << (4 * x);
      }
      C = (t < len) ? nc : C;
    }
    const uint32_t Clo = (uint32_t)C, Chi = (uint32_t)(C >> 32);
    uint32_t cur = (uint32_t)bl;
    int bnd = 0;
#pragma unroll
    for (int c = 63; c >= 0; --c) {
      bnd = (tid == c) ? (int)cur : bnd;
      const uint32_t lo = (uint32_t)__builtin_amdgcn_readlane((int)Clo, c);
      const uint32_t hi = (uint32_t)__builtin_amdgcn_readlane((int)Chi, c);
      const uint64_t cc = ((uint64_t)hi << 32) | lo;
      cur = (uint32_t)((cc >> (4 * cur)) & 15u);
    }
    int tag = bnd;
#pragma unroll
    for (int k = 8; k >= 1; --k) {
      const int t = 8 * tid + k;
      const int tt = (t < 512) ? t : 511;
      const int nt = bp_s[tt * NL + tag];
      tag = (t < len) ? nt : tag;
      tags_s[t - 1] = (unsigned char)tag;
    }
    __syncthreads();
    for (int i = tid; i < EMN; i += 64) {
      const int t = i / NL;
      const int l = i - t * NL;
      out[1 + (size_t)b * EMN + i] =
          (t < len && l == (int)tags_s[t]) ? 1.0f : 0.0f;
    }

  } else if (blk < 128) {
    // ================= numerator =================
    const int b   = blk - 64;
    const int len = lens[b];
    const float* emb = logits + (size_t)b * EMN;
    for (int t = tid; t < SS; t += 64) {
      const int v = labels[b * SS + t];
      lab[t] = (v == -100) ? 0 : v;
    }
    __syncthreads();
    float contrib = 0.0f;
    for (int t = tid; t < SS; t += 64) {
      if (t >= 1 && t < len)
        contrib += emb[t * NL + lab[t]] + trans[lab[t - 1] * NL + lab[t]];
    }
#pragma unroll
    for (int off = 32; off >= 1; off >>= 1)
      contrib += __shfl_xor(contrib, off, 64);
    if (tid == 0) {
      const int l0 = lab[0];
      num_den[b] = start_t[l0] + emb[l0] + contrib + end_t[lab[len - 1]];
    }

  } else {
    // ================= lognorm segment scan, 3 chains per wave =================
    const int id   = blk - 128;        // 0..1535
    const int pair = id / 3;           // (b, sg)
    const int wv   = id - pair * 3;    // which e-triple
    const int b    = pair >> 3;
    const int sg   = pair & 7;
    const int e0   = 3 * wv;           // chains e0, e0+1, e0+2
    const int len  = lens[b];
    const float* emb = logits + (size_t)b * EMN;
    float tc[NL];
#pragma unroll
    for (int i = 0; i < NL; ++i) tc[i] = trans[i * NL + j];
    float s0[NL], s1[NL], s2[NL];
#pragma unroll
    for (int i = 0; i < NL; ++i) {
      s0[i] = (i == e0)     ? 0.0f : NEG;
      s1[i] = (i == e0 + 1) ? 0.0f : NEG;
      s2[i] = (i == e0 + 2) ? 0.0f : NEG;
    }
    float my0 = (j == e0)     ? 0.0f : NEG;
    float my1 = (j == e0 + 1) ? 0.0f : NEG;
    float my2 = (j == e0 + 2) ? 0.0f : NEG;
    const int tbeg  = 64 * sg + 1;
    const int tlast = (64 * sg + 64 < 511) ? 64 * sg + 64 : 511;
    float eA = emb[tbeg * NL + j],       eB = emb[(tbeg + 1) * NL + j];
    float eC = emb[(tbeg + 2) * NL + j], eD = emb[(tbeg + 3) * NL + j];
    for (int t = tbeg; t <= tlast; ++t) {
      if (t >= len) break;             // prefix mask: rest are identity steps
      float c0[NL], c1[NL], c2[NL];
#pragma unroll
      for (int i = 0; i < NL; ++i) {
        c0[i] = s0[i] + tc[i];
        c1[i] = s1[i] + tc[i];
        c2[i] = s2[i] + tc[i];
      }
      const float m0 = fmaxf(fmaxf(fmaxf(fmaxf(c0[0], c0[1]), fmaxf(c0[2], c0[3])),
                                   fmaxf(fmaxf(c0[4], c0[5]), fmaxf(c0[6], c0[7]))), c0[8]);
      const float m1 = fmaxf(fmaxf(fmaxf(fmaxf(c1[0], c1[1]), fmaxf(c1[2], c1[3])),
                                   fmaxf(fmaxf(c1[4], c1[5]), fmaxf(c1[6], c1[7]))), c1[8]);
      const float m2 = fmaxf(fmaxf(fmaxf(fmaxf(c2[0], c2[1]), fmaxf(c2[2], c2[3])),
                                   fmaxf(fmaxf(c2[4], c2[5]), fmaxf(c2[6], c2[7]))), c2[8]);
      float u0 = 0.0f, u1 = 0.0f, u2 = 0.0f;
#pragma unroll
      for (int i = 0; i < NL; ++i) {
        u0 += __expf(c0[i] - m0);
        u1 += __expf(c1[i] - m1);
        u2 += __expf(c2[i] - m2);
      }
      my0 = m0 + __logf(u0) + eA;
      my1 = m1 + __logf(u1) + eA;
      my2 = m2 + __logf(u2) + eA;
#pragma unroll
      for (int i = 0; i < NL; ++i) {
        s0[i] = readlane_f(my0, i);
        s1[i] = readlane_f(my1, i);
        s2[i] = readlane_f(my2, i);
      }
      eA = eB; eB = eC; eC = eD;
      eD = emb[(t + 4) * NL + j];
    }
    if (tid < NL) {
      float* M = segmat + (size_t)(b * NSEG + sg) * 81;
      M[(e0    ) * NL + tid] = my0;
      M[(e0 + 1) * NL + tid] = my1;
      M[(e0 + 2) * NL + tid] = my2;
    }
  }
}

// ---------------------------------------------------------------------------
// Kernel 3: combine + loss — per batch, chain the 8 segment matrices, get
// den = logsumexp(v + end_t), then atomically accumulate (den-num)/64.
// ---------------------------------------------------------------------------
__global__ __launch_bounds__(64) void combine_kernel(
    const float* __restrict__ logits, const float* __restrict__ segmat,
    const float* __restrict__ start_t, const float* __restrict__ end_t,
    const float* __restrict__ num_den, float* __restrict__ out) {
  const int b   = blockIdx.x;
  const int tid = threadIdx.x;
  const int j   = (tid < NL) ? tid : NL - 1;
  float s[NL];
#pragma unroll
  for (int i = 0; i < NL; ++i) s[i] = start_t[i] + logits[(size_t)b * EMN + i];
  float mcur[NL], mnxt[NL];
  {
    const float* M = segmat + (size_t)(b * NSEG) * 81;
#pragma unroll
    for (int i = 0; i < NL; ++i) mcur[i] = M[i * NL + j];
  }
  for (int sg = 0; sg < NSEG; ++sg) {
    if (sg + 1 < NSEG) {
      const float* M = segmat + (size_t)(b * NSEG + sg + 1) * 81;
#pragma unroll
      for (int i = 0; i < NL; ++i) mnxt[i] = M[i * NL + j];
    }
    float c[NL];
#pragma unroll
    for (int i = 0; i < NL; ++i) c[i] = s[i] + mcur[i];
    const float x01 = fmaxf(c[0], c[1]), x23 = fmaxf(c[2], c[3]);
    const float x45 = fmaxf(c[4], c[5]), x67 = fmaxf(c[6], c[7]);
    const float m = fmaxf(fmaxf(fmaxf(x01, x23), fmaxf(x45, x67)), c[8]);
    float sum = 0.0f;
#pragma unroll
    for (int i = 0; i < NL; ++i) sum += __expf(c[i] - m);
    const float nxt = m + __logf(sum);
#pragma unroll
    for (int i = 0; i < NL; ++i) s[i] = readlane_f(nxt, i);
#pragma unroll
    for (int i = 0; i < NL; ++i) mcur[i] = mnxt[i];
  }
  float c[NL];
#pragma unroll
  for (int i = 0; i < NL; ++i) c[i] = s[i] + end_t[i];
  const float x01 = fmaxf(c[0], c[1]), x23 = fmaxf(c[2], c[3]);
  const float x45 = fmaxf(c[4], c[5]), x67 = fmaxf(c[6], c[7]);
  const float m = fmaxf(fmaxf(fmaxf(x01, x23), fmaxf(x45, x67)), c[8]);
  float sum = 0.0f;
#pragma unroll
  for (int i = 0; i < NL; ++i) sum += __expf(c[i] - m);
  if (tid == 0) {
    const float den = m + __logf(sum);
    atomicAdd(out, (den - num_den[b]) * (1.0f / 64.0f));
  }
}

extern "C" void kernel_launch(void* const* d_in, const int* in_sizes, int n_in,
                              void* d_out, int out_size, void* d_ws, size_t ws_size,
                              hipStream_t stream) {
  const float* hidden  = (const float*)d_in[0];
  const int*   mask    = (const int*)d_in[1];
  const int*   labels  = (const int*)d_in[2];
  const float* W       = (const float*)d_in[3];
  const float* bias    = (const float*)d_in[4];
  const float* start_t = (const float*)d_in[5];
  const float* end_t   = (const float*)d_in[6];
  const float* trans   = (const float*)d_in[7];
  float* out = (float*)d_out;

  float* logits  = (float*)d_ws;                      // 294912 floats
  float* segmat  = logits + (size_t)NROWS * NL;       // 64*8*81 floats
  float* num_den = segmat + (size_t)BB * NSEG * 81;   // 64 floats (num)
  int*   lens    = (int*)(num_den + 128);             // 64 ints

  hipMemsetAsync(out, 0, sizeof(float), stream);      // zero loss accumulator
  logits_kernel<<<2048, 256, 0, stream>>>(hidden, W, bias, mask, logits, lens);
  scan_kernel<<<1664, 64, 0, stream>>>(logits, labels, start_t, end_t, trans,
                                       out, num_den, lens, segmat);
  combine_kernel<<<64, 64, 0, stream>>>(logits, segmat, start_t, end_t,
                                        num_den, out);
}